// Round 12
// baseline (80.927 us; speedup 1.0000x reference)
//
#include <hip/hip_runtime.h>
#include <stdint.h>

// NFP pooling: out[b,o,i,j] = -sum_c |x[b,c,i+1,j+1] - x[b,c,i+di,j+dj]|
// x: (8,128,224,224) f32 -> out: (8,8,222,222) f32.
//
// R12: R10 geometry (TROWS=4/SROWS=6/KC=4, 448 blocks, XCD pinning) with
// the per-round vmcnt(0) barrier drain replaced by a 3-deep counted-vmcnt
// pipeline (T3/T4): 3 LDS buffers, s_waitcnt vmcnt(6) + raw s_barrier, so
// 2 stages' DMAs stay in flight across every barrier. 448 threads/block ->
// exactly 3 gload16/thread/stage (uniform vmcnt accounting).

constexpr int C = 128;
constexpr int H = 224;
constexpr int W = 224;
constexpr int HO = 222;
constexpr int WO = 222;
constexpr int PLANE = H * W;              // 50176
constexpr int OPLANE = HO * WO;           // 49284
constexpr int KC = 4;                     // channels per stage
constexpr int ROUNDS = C / KC;            // 32
constexpr int TROWS = 4;                  // output rows per tile
constexpr int SROWS = 6;                  // staged input rows
constexpr int NT = 56;                    // row tiles per batch
constexpr int NBLK = 8 * NT;              // 448
constexpr int NTHR = 448;                 // 7 waves
constexpr int SLOTS = KC * SROWS * (W / 4);   // 1344 = 448*3
constexpr int BUF_F = SLOTS * 4;          // floats per buffer

__device__ __forceinline__ void gload16(const float* g, float* l) {
    __builtin_amdgcn_global_load_lds(
        (const __attribute__((address_space(1))) void*)g,
        (__attribute__((address_space(3))) void*)l, 16, 0, 0);
}

__global__ __launch_bounds__(NTHR, 1)
void nfp_sad_kernel(const float* __restrict__ x, float* __restrict__ out) {
    __shared__ float lds[3][BUF_F];       // 3 x 21,504 B = 64,512 B

    int bid = blockIdx.x;
    int b = bid & 7;                      // batch == XCD (448 = 8*56)
    int t = bid >> 3;                     // row tile 0..55
    int i0 = t * TROWS;                   // staged input rows i0..i0+5
    int tid = threadIdx.x;

    // staging slots: v = j*448 + tid (j=0..2), v < 1344 exactly.
    // v -> c = v/336, r = (v%336)/56, k = v%56 ; row clamped to 223.
    const float* xb = x + (size_t)b * C * PLANE;
    int goff[3];
#pragma unroll
    for (int j = 0; j < 3; ++j) {
        int v = j * NTHR + tid;
        int c = v / 336, rem = v % 336;
        int r = rem / 56, k = rem % 56;
        int row = i0 + r; if (row > H - 1) row = H - 1;
        goff[j] = c * PLANE + row * W + k * 4;
    }

    // compute role: tid < 222; rp = tid/111 (0..1), cp = tid%111
    bool act = tid < 222;
    int rp = act ? (tid / 111) : 0;
    int cp = act ? (tid % 111) : 0;

    float acc0[8][2], acc1[8][2];
#pragma unroll
    for (int o = 0; o < 8; ++o) {
        acc0[o][0] = acc0[o][1] = 0.0f;
        acc1[o][0] = acc1[o][1] = 0.0f;
    }

#define STAGE(sidx, bufi) do {                                          \
        int off_ = (sidx) * KC * PLANE;                                 \
        float* dst_ = &lds[bufi][0];                                    \
        gload16(xb + off_ + goff[0], dst_ + (0 * NTHR + tid) * 4);      \
        gload16(xb + off_ + goff[1], dst_ + (1 * NTHR + tid) * 4);      \
        gload16(xb + off_ + goff[2], dst_ + (2 * NTHR + tid) * 4);      \
    } while (0)

#define COMPUTE(bufi) do {                                              \
    if (act) {                                                          \
        const float* Bf = &lds[bufi][0];                                \
        _Pragma("unroll")                                               \
        for (int c = 0; c < KC; ++c) {                                  \
            const float* pc = Bf + (c * SROWS + 2 * rp) * W + 2 * cp;   \
            float v0[4], v1[4], v2[4], v3[4];                           \
            *(float2*)&v0[0] = *(const float2*)(pc);                    \
            *(float2*)&v0[2] = *(const float2*)(pc + 2);                \
            *(float2*)&v1[0] = *(const float2*)(pc + W);                \
            *(float2*)&v1[2] = *(const float2*)(pc + W + 2);            \
            *(float2*)&v2[0] = *(const float2*)(pc + 2 * W);            \
            *(float2*)&v2[2] = *(const float2*)(pc + 2 * W + 2);        \
            *(float2*)&v3[0] = *(const float2*)(pc + 3 * W);            \
            *(float2*)&v3[2] = *(const float2*)(pc + 3 * W + 2);        \
            float hh1[3], hh2[3], DR[3], DL[3], Vv[2];                  \
            _Pragma("unroll")                                           \
            for (int k = 0; k < 3; ++k) {                               \
                hh1[k] = __builtin_fabsf(v1[k + 1] - v1[k]);            \
                hh2[k] = __builtin_fabsf(v2[k + 1] - v2[k]);            \
                DR[k]  = __builtin_fabsf(v1[k + 1] - v2[k]);            \
                DL[k]  = __builtin_fabsf(v1[k] - v2[k + 1]);            \
            }                                                           \
            Vv[0] = __builtin_fabsf(v1[1] - v2[1]);                     \
            Vv[1] = __builtin_fabsf(v1[2] - v2[2]);                     \
            _Pragma("unroll")                                           \
            for (int q = 0; q < 2; ++q) {                               \
                float c1 = v1[q + 1], c2 = v2[q + 1];                   \
                acc0[0][q] += __builtin_fabsf(c1 - v0[q]);              \
                acc0[1][q] += __builtin_fabsf(c1 - v0[q + 1]);          \
                acc0[2][q] += __builtin_fabsf(c1 - v0[q + 2]);          \
                acc0[3][q] += hh1[q];                                   \
                acc0[4][q] += hh1[q + 1];                               \
                acc0[5][q] += DR[q];                                    \
                acc0[6][q] += Vv[q];                                    \
                acc0[7][q] += DL[q + 1];                                \
                acc1[0][q] += DL[q];                                    \
                acc1[1][q] += Vv[q];                                    \
                acc1[2][q] += DR[q + 1];                                \
                acc1[3][q] += hh2[q];                                   \
                acc1[4][q] += hh2[q + 1];                               \
                acc1[5][q] += __builtin_fabsf(c2 - v3[q]);              \
                acc1[6][q] += __builtin_fabsf(c2 - v3[q + 1]);          \
                acc1[7][q] += __builtin_fabsf(c2 - v3[q + 2]);          \
            }                                                           \
        }                                                               \
    }                                                                   \
} while (0)

    // prologue: fill the 3-deep pipeline (9 loads in flight per wave)
    STAGE(0, 0);
    STAGE(1, 1);
    STAGE(2, 2);

    int buf = 0;
    for (int rd = 0; rd < ROUNDS - 3; ++rd) {        // rd = 0..28
        asm volatile("s_waitcnt vmcnt(6)" ::: "memory");  // stage(rd) landed
        __builtin_amdgcn_s_barrier();                // all waves see it
        __builtin_amdgcn_sched_barrier(0);
        COMPUTE(buf);
        __builtin_amdgcn_sched_barrier(0);
        __builtin_amdgcn_s_barrier();                // all done reading buf
        STAGE(rd + 3, buf);                          // refill into freed buf
        buf = (buf == 2) ? 0 : buf + 1;
    }
    // epilogue: rd = 29, 30, 31 (no more staging; counted waits 6 -> 3 -> 0)
    asm volatile("s_waitcnt vmcnt(6)" ::: "memory");
    __builtin_amdgcn_s_barrier();
    __builtin_amdgcn_sched_barrier(0);
    COMPUTE(2);
    asm volatile("s_waitcnt vmcnt(3)" ::: "memory");
    __builtin_amdgcn_s_barrier();
    __builtin_amdgcn_sched_barrier(0);
    COMPUTE(0);
    asm volatile("s_waitcnt vmcnt(0)" ::: "memory");
    __builtin_amdgcn_s_barrier();
    __builtin_amdgcn_sched_barrier(0);
    COMPUTE(1);

    if (act) {
        int r0 = i0 + 2 * rp;
        float* ob = out + (size_t)b * 8 * OPLANE + 2 * cp;
#pragma unroll
        for (int o = 0; o < 8; ++o) {
            float* op = ob + (size_t)o * OPLANE;
            if (r0 < HO)
                *(float2*)(op + (size_t)r0 * WO) = make_float2(-acc0[o][0], -acc0[o][1]);
            if (r0 + 1 < HO)
                *(float2*)(op + (size_t)(r0 + 1) * WO) = make_float2(-acc1[o][0], -acc1[o][1]);
        }
    }
}

extern "C" void kernel_launch(void* const* d_in, const int* in_sizes, int n_in,
                              void* d_out, int out_size, void* d_ws, size_t ws_size,
                              hipStream_t stream) {
    const float* x = (const float*)d_in[0];
    float* out = (float*)d_out;
    nfp_sad_kernel<<<NBLK, NTHR, 0, stream>>>(x, out);
}

// Round 13
// 53.820 us; speedup vs baseline: 1.5037x; 1.5037x over previous
//
#include <hip/hip_runtime.h>
#include <stdint.h>

// NFP pooling: out[b,o,i,j] = -sum_c |x[b,c,i+1,j+1] - x[b,c,i+di,j+dj]|
// x: (8,128,224,224) f32 -> out: (8,8,222,222) f32.
//
// R13: R10 geometry verbatim (256 thr, 448 blocks, KC=4, TROWS=4/SROWS=6,
// XCD pinning) with the sync structure replaced: 3 LDS buffers, ONE raw
// s_barrier per round, per-wave counted vmcnt (wave0: 6 loads/stage, waits
// vmcnt(6); waves1-3: 5 loads, wait vmcnt(5)), 2-stage-ahead prefetch.
// Stage rd+2 overwrites buf[(rd-1)%3], whose readers finished before this
// round's barrier -> single barrier orders both hazards. No sched_barrier
// (m141), no vmcnt(0) in the loop (T4).

constexpr int C = 128;
constexpr int H = 224;
constexpr int W = 224;
constexpr int HO = 222;
constexpr int WO = 222;
constexpr int PLANE = H * W;              // 50176
constexpr int OPLANE = HO * WO;           // 49284
constexpr int KC = 4;                     // channels per stage
constexpr int ROUNDS = C / KC;            // 32
constexpr int TROWS = 4;                  // output rows per tile
constexpr int SROWS = 6;                  // staged input rows
constexpr int NT = 56;                    // row tiles per batch
constexpr int NBLK = 8 * NT;              // 448
constexpr int NTHR = 256;
constexpr int SLOTS = KC * SROWS * (W / 4);   // 1344 16-B slots per buffer
constexpr int BUF_F = SLOTS * 4;

__device__ __forceinline__ void gload16(const float* g, float* l) {
    __builtin_amdgcn_global_load_lds(
        (const __attribute__((address_space(1))) void*)g,
        (__attribute__((address_space(3))) void*)l, 16, 0, 0);
}

__global__ __launch_bounds__(NTHR, 1)
void nfp_sad_kernel(const float* __restrict__ x, float* __restrict__ out) {
    __shared__ float lds[3][BUF_F];       // 3 x 21,504 B = 64,512 B

    int bid = blockIdx.x;
    int b = bid & 7;                      // batch == XCD (448 = 8*56)
    int t = bid >> 3;                     // row tile 0..55
    int i0 = t * TROWS;                   // staged input rows i0..i0+5
    int tid = threadIdx.x;

    // staging slots: v = j*256 + tid, v < 1344 (j=0..4 full, j=5: tid<64).
    // v -> c = v/336, r = (v%336)/56, k = v%56 ; row clamped to 223.
    const float* xb = x + (size_t)b * C * PLANE;
    int goff[6];
#pragma unroll
    for (int j = 0; j < 6; ++j) {
        int v = j * NTHR + tid;
        int vv = v < SLOTS ? v : SLOTS - 1;
        int c = vv / 336, rem = vv % 336;
        int r = rem / 56, k = rem % 56;
        int row = i0 + r; if (row > H - 1) row = H - 1;
        goff[j] = c * PLANE + row * W + k * 4;
    }
    const bool tail = (tid < SLOTS - 5 * NTHR);   // 64 tail slots -> wave 0

    // compute role: tid < 222; rp = tid/111 (0..1), cp = tid%111
    bool act = tid < 222;
    int rp = act ? (tid / 111) : 0;
    int cp = act ? (tid % 111) : 0;

    float acc0[8][2], acc1[8][2];
#pragma unroll
    for (int o = 0; o < 8; ++o) {
        acc0[o][0] = acc0[o][1] = 0.0f;
        acc1[o][0] = acc1[o][1] = 0.0f;
    }

#define STAGE(sidx, bufi) do {                                          \
        int off_ = (sidx) * KC * PLANE;                                 \
        float* dst_ = &lds[bufi][0];                                    \
        gload16(xb + off_ + goff[0], dst_ + (0 * NTHR + tid) * 4);      \
        gload16(xb + off_ + goff[1], dst_ + (1 * NTHR + tid) * 4);      \
        gload16(xb + off_ + goff[2], dst_ + (2 * NTHR + tid) * 4);      \
        gload16(xb + off_ + goff[3], dst_ + (3 * NTHR + tid) * 4);      \
        gload16(xb + off_ + goff[4], dst_ + (4 * NTHR + tid) * 4);      \
        if (tail)                                                       \
            gload16(xb + off_ + goff[5], dst_ + (5 * NTHR + tid) * 4);  \
    } while (0)

    // wait until only the most recent stage remains in flight
#define WAIT_ONE() do {                                                 \
        if (tail) asm volatile("s_waitcnt vmcnt(6)" ::: "memory");      \
        else      asm volatile("s_waitcnt vmcnt(5)" ::: "memory");      \
    } while (0)

#define COMPUTE(bufi) do {                                              \
    if (act) {                                                          \
        const float* Bf = &lds[bufi][0];                                \
        _Pragma("unroll")                                               \
        for (int c = 0; c < KC; ++c) {                                  \
            const float* pc = Bf + (c * SROWS + 2 * rp) * W + 2 * cp;   \
            float v0[4], v1[4], v2[4], v3[4];                           \
            *(float2*)&v0[0] = *(const float2*)(pc);                    \
            *(float2*)&v0[2] = *(const float2*)(pc + 2);                \
            *(float2*)&v1[0] = *(const float2*)(pc + W);                \
            *(float2*)&v1[2] = *(const float2*)(pc + W + 2);            \
            *(float2*)&v2[0] = *(const float2*)(pc + 2 * W);            \
            *(float2*)&v2[2] = *(const float2*)(pc + 2 * W + 2);        \
            *(float2*)&v3[0] = *(const float2*)(pc + 3 * W);            \
            *(float2*)&v3[2] = *(const float2*)(pc + 3 * W + 2);        \
            float hh1[3], hh2[3], DR[3], DL[3], Vv[2];                  \
            _Pragma("unroll")                                           \
            for (int k = 0; k < 3; ++k) {                               \
                hh1[k] = __builtin_fabsf(v1[k + 1] - v1[k]);            \
                hh2[k] = __builtin_fabsf(v2[k + 1] - v2[k]);            \
                DR[k]  = __builtin_fabsf(v1[k + 1] - v2[k]);            \
                DL[k]  = __builtin_fabsf(v1[k] - v2[k + 1]);            \
            }                                                           \
            Vv[0] = __builtin_fabsf(v1[1] - v2[1]);                     \
            Vv[1] = __builtin_fabsf(v1[2] - v2[2]);                     \
            _Pragma("unroll")                                           \
            for (int q = 0; q < 2; ++q) {                               \
                float c1 = v1[q + 1], c2 = v2[q + 1];                   \
                acc0[0][q] += __builtin_fabsf(c1 - v0[q]);              \
                acc0[1][q] += __builtin_fabsf(c1 - v0[q + 1]);          \
                acc0[2][q] += __builtin_fabsf(c1 - v0[q + 2]);          \
                acc0[3][q] += hh1[q];                                   \
                acc0[4][q] += hh1[q + 1];                               \
                acc0[5][q] += DR[q];                                    \
                acc0[6][q] += Vv[q];                                    \
                acc0[7][q] += DL[q + 1];                                \
                acc1[0][q] += DL[q];                                    \
                acc1[1][q] += Vv[q];                                    \
                acc1[2][q] += DR[q + 1];                                \
                acc1[3][q] += hh2[q];                                   \
                acc1[4][q] += hh2[q + 1];                               \
                acc1[5][q] += __builtin_fabsf(c2 - v3[q]);              \
                acc1[6][q] += __builtin_fabsf(c2 - v3[q + 1]);          \
                acc1[7][q] += __builtin_fabsf(c2 - v3[q + 2]);          \
            }                                                           \
        }                                                               \
    }                                                                   \
} while (0)

    // prologue: 2 stages in flight
    STAGE(0, 0);
    STAGE(1, 1);

    // steady state: one barrier per round, vmcnt never drained below one stage
    for (int rd = 0; rd < ROUNDS - 2; ++rd) {        // rd = 0..29
        WAIT_ONE();                                  // stage rd landed (this wave)
        __builtin_amdgcn_s_barrier();                // landed for all waves; and
                                                     // buf[(rd+2)%3] readers done
        STAGE(rd + 2, (rd + 2) % 3);                 // refill, 2 ahead
        COMPUTE(rd % 3);
    }
    // epilogue: rd = 30 (stage 31 still in flight), rd = 31
    WAIT_ONE();
    __builtin_amdgcn_s_barrier();
    COMPUTE(0);                                      // 30 % 3
    asm volatile("s_waitcnt vmcnt(0)" ::: "memory");
    __builtin_amdgcn_s_barrier();
    COMPUTE(1);                                      // 31 % 3

    if (act) {
        int r0 = i0 + 2 * rp;
        float* ob = out + (size_t)b * 8 * OPLANE + 2 * cp;
#pragma unroll
        for (int o = 0; o < 8; ++o) {
            float* op = ob + (size_t)o * OPLANE;
            if (r0 < HO)
                *(float2*)(op + (size_t)r0 * WO) = make_float2(-acc0[o][0], -acc0[o][1]);
            if (r0 + 1 < HO)
                *(float2*)(op + (size_t)(r0 + 1) * WO) = make_float2(-acc1[o][0], -acc1[o][1]);
        }
    }
}

extern "C" void kernel_launch(void* const* d_in, const int* in_sizes, int n_in,
                              void* d_out, int out_size, void* d_ws, size_t ws_size,
                              hipStream_t stream) {
    const float* x = (const float*)d_in[0];
    float* out = (float*)d_out;
    nfp_sad_kernel<<<NBLK, NTHR, 0, stream>>>(x, out);
}